// Round 1
// baseline (48.987 us; speedup 1.0000x reference)
//
#include <hip/hip_runtime.h>

// MPO/TT embedding: out[t] = A2[h(t)] (16x64) . B3[l(t)] (64x48)
// cores: c0 (1,8,4,32) c1 (32,8,4,64) c2 (64,8,4,64) c3 (64,8,4,24) c4 (24,8,3,1)
// v = i1*4096+i2*512+i3*64+i4*8+i5 ; o = o1*192+o2*48+o3*12+o4*3+o5
// h = v>>9 = i1*8+i2 ; l = v&511 = i3*64+i4*8+i5 ; l2 = l&63 ; i3 = l>>6
// o12 = o1*4+o2 (16) ; o345 = o3*12+o4*3+o5 (48) ; o = o12*48+o345

// A2T[h][r2][o12]  (64*64*16 f32, 256KB), stored so [h][r2] row is 4 float4s (o12 quads)
__global__ __launch_bounds__(256) void k_a2t(const float* __restrict__ c0,
                                             const float* __restrict__ c1,
                                             float* __restrict__ A2T) {
    int h = blockIdx.x;            // 64
    int t = threadIdx.x;           // 256
    int r2 = t >> 2, b = t & 3;    // b = o1, o2 in 0..3 -> o12 = 4b+o2
    int i1 = h >> 3, i2 = h & 7;
    const float* c0p = c0 + i1 * 128 + b * 32;          // [i1][o1=b][r1]
    const float* c1p = c1 + i2 * 256 + r2;              // [r1][i2][o2][r2]
    float a0 = 0.f, a1 = 0.f, a2 = 0.f, a3 = 0.f;
#pragma unroll
    for (int r1 = 0; r1 < 32; ++r1) {
        float a = c0p[r1];
        const float* p = c1p + r1 * 2048;
        a0 += a * p[0];
        a1 += a * p[64];
        a2 += a * p[128];
        a3 += a * p[192];
    }
    reinterpret_cast<float4*>(A2T)[(h * 64 + r2) * 4 + b] =
        make_float4(a0, a1, a2, a3);
}

// B4[l2][r3][o45]  (64*64*12 f32, 192KB)
__global__ __launch_bounds__(256) void k_b4(const float* __restrict__ c3,
                                            const float* __restrict__ c4,
                                            float* __restrict__ B4) {
    int l2 = blockIdx.x;           // 64
    int t = threadIdx.x;           // 256
    int r3 = t >> 2, m = t & 3;    // m = o4, o5 = 0..2
    int i4 = l2 >> 3, i5 = l2 & 7;
    const float* c3p = c3 + r3 * 768 + i4 * 96 + m * 24;  // [r3][i4][o4=m][r4]
    const float* c4p = c4 + i5 * 3;                        // [r4][i5][o5]
    float a0 = 0.f, a1 = 0.f, a2 = 0.f;
#pragma unroll
    for (int r4 = 0; r4 < 24; ++r4) {
        float a = c3p[r4];
        a0 += a * c4p[r4 * 24 + 0];
        a1 += a * c4p[r4 * 24 + 1];
        a2 += a * c4p[r4 * 24 + 2];
    }
    float* o = B4 + (l2 * 64 + r3) * 12 + m * 3;
    o[0] = a0; o[1] = a1; o[2] = a2;
}

// B3p[l][r2][jj][4] (512*64*16*4 f32, 8MB): jj in 0..15, elems {o345=3jj,3jj+1,3jj+2,pad0}
__global__ __launch_bounds__(256) void k_b3(const float* __restrict__ c2,
                                            const float* __restrict__ B4,
                                            float* __restrict__ B3p) {
    int l = blockIdx.x;            // 512
    int t = threadIdx.x;           // 256
    int r2 = t >> 2, q = t & 3;    // q = o3; covers o45 in [0,12)
    int i3 = l >> 6, l2 = l & 63;
    const float* c2p = c2 + r2 * 2048 + i3 * 256 + q * 64;     // [r2][i3][o3=q][r3]
    const float4* b4p = reinterpret_cast<const float4*>(B4) + l2 * 192;  // [l2][r3*12]/4
    float acc[4][3] = {};
#pragma unroll 4
    for (int r3 = 0; r3 < 64; ++r3) {
        float a = c2p[r3];
        float4 b0 = b4p[r3 * 3 + 0];
        float4 b1 = b4p[r3 * 3 + 1];
        float4 b2 = b4p[r3 * 3 + 2];
        acc[0][0] += a * b0.x; acc[0][1] += a * b0.y; acc[0][2] += a * b0.z;
        acc[1][0] += a * b0.w; acc[1][1] += a * b1.x; acc[1][2] += a * b1.y;
        acc[2][0] += a * b1.z; acc[2][1] += a * b1.w; acc[2][2] += a * b2.x;
        acc[3][0] += a * b2.y; acc[3][1] += a * b2.z; acc[3][2] += a * b2.w;
    }
    float4* o = reinterpret_cast<float4*>(B3p) + (l * 64 + r2) * 16 + q * 4;
#pragma unroll
    for (int g = 0; g < 4; ++g)
        o[g] = make_float4(acc[g][0], acc[g][1], acc[g][2], 0.f);
}

// main: one wave per token; lane = (q=o12quad)*16 + jj(o345 group)
__global__ __launch_bounds__(256) void k_main(const int* __restrict__ ids,
                                              const float* __restrict__ A2T,
                                              const float* __restrict__ B3p,
                                              float* __restrict__ out,
                                              int n_tokens) {
    int t = threadIdx.x;
    int wave = t >> 6, lane = t & 63;
    int token = blockIdx.x * 4 + wave;
    if (token >= n_tokens) return;
    int q = lane >> 4, jj = lane & 15;
    int v = ids[token];
    int h = v >> 9, l = v & 511;
    const float4* A = reinterpret_cast<const float4*>(A2T) + h * 256 + q;   // [(h*64+r2)*4+q]
    const float4* B = reinterpret_cast<const float4*>(B3p) + l * 1024 + jj; // [(l*64+r2)*16+jj]
    float acc[4][3] = {};
#pragma unroll 8
    for (int r2 = 0; r2 < 64; ++r2) {
        float4 a = A[r2 * 4];
        float4 b = B[r2 * 16];
        acc[0][0] += a.x * b.x; acc[0][1] += a.x * b.y; acc[0][2] += a.x * b.z;
        acc[1][0] += a.y * b.x; acc[1][1] += a.y * b.y; acc[1][2] += a.y * b.z;
        acc[2][0] += a.z * b.x; acc[2][1] += a.z * b.y; acc[2][2] += a.z * b.z;
        acc[3][0] += a.w * b.x; acc[3][1] += a.w * b.y; acc[3][2] += a.w * b.z;
    }
    float* o = out + (size_t)token * 768 + 3 * jj;
#pragma unroll
    for (int qq = 0; qq < 4; ++qq) {
        int o12 = 4 * q + qq;
        o[o12 * 48 + 0] = acc[qq][0];
        o[o12 * 48 + 1] = acc[qq][1];
        o[o12 * 48 + 2] = acc[qq][2];
    }
}

extern "C" void kernel_launch(void* const* d_in, const int* in_sizes, int n_in,
                              void* d_out, int out_size, void* d_ws, size_t ws_size,
                              hipStream_t stream) {
    const int*   ids = (const int*)d_in[0];
    const float* c0  = (const float*)d_in[1];
    const float* c1  = (const float*)d_in[2];
    const float* c2  = (const float*)d_in[3];
    const float* c3  = (const float*)d_in[4];
    const float* c4  = (const float*)d_in[5];
    float* out = (float*)d_out;

    char* ws = (char*)d_ws;
    float* A2T = (float*)(ws + 0);          // 262144 B
    float* B4  = (float*)(ws + 262144);     // 196608 B
    float* B3p = (float*)(ws + 524288);     // 8388608 B  (total 8.5 MB)

    int n_tokens = in_sizes[0];             // 8*512 = 4096

    k_a2t<<<64, 256, 0, stream>>>(c0, c1, A2T);
    k_b4 <<<64, 256, 0, stream>>>(c3, c4, B4);
    k_b3 <<<512, 256, 0, stream>>>(c2, B4, B3p);
    k_main<<<(n_tokens + 3) / 4, 256, 0, stream>>>(ids, A2T, B3p, out, n_tokens);
}

// Round 2
// 42.112 us; speedup vs baseline: 1.1633x; 1.1633x over previous
//
#include <hip/hip_runtime.h>

// MPO/TT embedding: out[t] = A2[h(t)] (16x64) . B3[l(t)] (64x48)
// cores: c0 (1,8,4,32) c1 (32,8,4,64) c2 (64,8,4,64) c3 (64,8,4,24) c4 (24,8,3,1)
// v = i1*4096+i2*512+i3*64+i4*8+i5 ; o = o1*192+o2*48+o3*12+o4*3+o5
// h = v>>9 ; l = v&511 ; l2 = l&63 ; i3 = l>>6
// o12 = o1*4+o2 (16) ; o345 = o3*12+o4*3+o5 (48) ; o = o12*48+o345

// Fused prep kernel:
//   blocks 0..511   : B3p[l][r2][jj][4] (8MB), B4[l2] recomputed in LDS per block
//   blocks 512..575 : A2T[h][r2][o12]   (256KB)
__global__ __launch_bounds__(256) void k_prep(const float* __restrict__ c0,
                                              const float* __restrict__ c1,
                                              const float* __restrict__ c2,
                                              const float* __restrict__ c3,
                                              const float* __restrict__ c4,
                                              float* __restrict__ A2T,
                                              float* __restrict__ B3p) {
    int t = threadIdx.x;
    if (blockIdx.x >= 512) {
        // ---- A2T: h = blockIdx-512 ----
        int h = blockIdx.x - 512;
        int r2 = t >> 2, b = t & 3;          // b = o1
        int i1 = h >> 3, i2 = h & 7;
        const float* c0p = c0 + i1 * 128 + b * 32;   // [i1][o1=b][r1]
        const float* c1p = c1 + i2 * 256 + r2;       // [r1][i2][o2][r2]
        float a0 = 0.f, a1 = 0.f, a2 = 0.f, a3 = 0.f;
#pragma unroll
        for (int r1 = 0; r1 < 32; ++r1) {
            float a = c0p[r1];
            const float* p = c1p + r1 * 2048;
            a0 += a * p[0];
            a1 += a * p[64];
            a2 += a * p[128];
            a3 += a * p[192];
        }
        reinterpret_cast<float4*>(A2T)[(h * 64 + r2) * 4 + b] =
            make_float4(a0, a1, a2, a3);
        return;
    }

    // ---- B3p for l = blockIdx ----
    int l = blockIdx.x;
    int i3 = l >> 6, l2 = l & 63;

    // stage B4[l2][r3][o45] (64*12 floats = 3KB) in LDS
    __shared__ float b4s[64 * 12];
    {
        int r3 = t >> 2, m = t & 3;          // m = o4
        int i4 = l2 >> 3, i5 = l2 & 7;
        const float* c3p = c3 + r3 * 768 + i4 * 96 + m * 24;  // [r3][i4][o4=m][r4]
        const float* c4p = c4 + i5 * 3;                       // [r4][i5][o5]
        float a0 = 0.f, a1 = 0.f, a2 = 0.f;
#pragma unroll
        for (int r4 = 0; r4 < 24; ++r4) {
            float a = c3p[r4];
            a0 += a * c4p[r4 * 24 + 0];
            a1 += a * c4p[r4 * 24 + 1];
            a2 += a * c4p[r4 * 24 + 2];
        }
        float* o = b4s + r3 * 12 + m * 3;
        o[0] = a0; o[1] = a1; o[2] = a2;
    }
    __syncthreads();

    int r2 = t >> 2, q = t & 3;              // q = o3
    const float* c2p = c2 + r2 * 2048 + i3 * 256 + q * 64;  // [r2][i3][o3=q][r3]
    const float4* b4p = reinterpret_cast<const float4*>(b4s);
    float acc[4][3] = {};
#pragma unroll 4
    for (int r3 = 0; r3 < 64; ++r3) {
        float a = c2p[r3];
        float4 b0 = b4p[r3 * 3 + 0];
        float4 b1 = b4p[r3 * 3 + 1];
        float4 b2 = b4p[r3 * 3 + 2];
        acc[0][0] += a * b0.x; acc[0][1] += a * b0.y; acc[0][2] += a * b0.z;
        acc[1][0] += a * b0.w; acc[1][1] += a * b1.x; acc[1][2] += a * b1.y;
        acc[2][0] += a * b1.z; acc[2][1] += a * b1.w; acc[2][2] += a * b2.x;
        acc[3][0] += a * b2.y; acc[3][1] += a * b2.z; acc[3][2] += a * b2.w;
    }
    float4* o = reinterpret_cast<float4*>(B3p) + (l * 64 + r2) * 16 + q * 4;
#pragma unroll
    for (int g = 0; g < 4; ++g)
        o[g] = make_float4(acc[g][0], acc[g][1], acc[g][2], 0.f);
}

// main: one wave per token; lane = (q=o12quad)*16 + jj(o345 group)
__global__ __launch_bounds__(256) void k_main(const int* __restrict__ ids,
                                              const float* __restrict__ A2T,
                                              const float* __restrict__ B3p,
                                              float* __restrict__ out,
                                              int n_tokens) {
    int t = threadIdx.x;
    int wave = t >> 6, lane = t & 63;
    int token = blockIdx.x * 4 + wave;
    if (token >= n_tokens) return;
    int q = lane >> 4, jj = lane & 15;
    int v = ids[token];
    int h = v >> 9, l = v & 511;
    const float4* A = reinterpret_cast<const float4*>(A2T) + h * 256 + q;   // [(h*64+r2)*4+q]
    const float4* B = reinterpret_cast<const float4*>(B3p) + l * 1024 + jj; // [(l*64+r2)*16+jj]
    float acc[4][3] = {};
#pragma unroll 8
    for (int r2 = 0; r2 < 64; ++r2) {
        float4 a = A[r2 * 4];
        float4 b = B[r2 * 16];
        acc[0][0] += a.x * b.x; acc[0][1] += a.x * b.y; acc[0][2] += a.x * b.z;
        acc[1][0] += a.y * b.x; acc[1][1] += a.y * b.y; acc[1][2] += a.y * b.z;
        acc[2][0] += a.z * b.x; acc[2][1] += a.z * b.y; acc[2][2] += a.z * b.z;
        acc[3][0] += a.w * b.x; acc[3][1] += a.w * b.y; acc[3][2] += a.w * b.z;
    }
    float* o = out + (size_t)token * 768 + 3 * jj;
#pragma unroll
    for (int qq = 0; qq < 4; ++qq) {
        int o12 = 4 * q + qq;
        o[o12 * 48 + 0] = acc[qq][0];
        o[o12 * 48 + 1] = acc[qq][1];
        o[o12 * 48 + 2] = acc[qq][2];
    }
}

extern "C" void kernel_launch(void* const* d_in, const int* in_sizes, int n_in,
                              void* d_out, int out_size, void* d_ws, size_t ws_size,
                              hipStream_t stream) {
    const int*   ids = (const int*)d_in[0];
    const float* c0  = (const float*)d_in[1];
    const float* c1  = (const float*)d_in[2];
    const float* c2  = (const float*)d_in[3];
    const float* c3  = (const float*)d_in[4];
    const float* c4  = (const float*)d_in[5];
    float* out = (float*)d_out;

    char* ws = (char*)d_ws;
    float* A2T = (float*)(ws + 0);          // 262144 B
    float* B3p = (float*)(ws + 262144);     // 8388608 B (total ~8.6 MB)

    int n_tokens = in_sizes[0];             // 8*512 = 4096

    k_prep<<<576, 256, 0, stream>>>(c0, c1, c2, c3, c4, A2T, B3p);
    k_main<<<(n_tokens + 3) / 4, 256, 0, stream>>>(ids, A2T, B3p, out, n_tokens);
}